// Round 2
// baseline (846.865 us; speedup 1.0000x reference)
//
#include <hip/hip_runtime.h>
#include <hip/hip_bf16.h>

// Decoder_12249246728712 — fused fp16-MFMA implementation.
//  * All conv stages: GEMMs OUT[d][o] = sum_{k,c} XT[d+k-2][c] * W[o][c][k],
//    XT transposed in LDS ([row=d][col=c], non-pow2 16B-aligned strides).
//  * MFMA 16x16x32 f16: A lane(m=l&15 row, k=(l>>4)*8+j), D lane(col=l&15, row=(l>>4)*4+r).
//  * ZERO-PAD SEMANTICS: every stage store zeroes rows with global d outside [0,512),
//    matching the reference's per-conv zero padding (this was the r1 accuracy bug).
//  * fp16 (not bf16) operands: 8x less rounding noise across the 8-stage chain.
//  * proj accumulated per d-tile into PROJ[35][144] fp32; out2 never materialized.

typedef _Float16 h16;
typedef _Float16 h16x8 __attribute__((ext_vector_type(8)));
typedef _Float16 h16x4 __attribute__((ext_vector_type(4)));
typedef float    f32x4 __attribute__((ext_vector_type(4)));

#define MFMA16(a,b,c) __builtin_amdgcn_mfma_f32_16x16x32_f16((a),(b),(c),0,0,0)

__device__ __forceinline__ int clampi(int x, int lo, int hi){ return x < lo ? lo : (x > hi ? hi : x); }
__device__ __forceinline__ float eluf(float v){ return v > 0.f ? v : (__expf(v) - 1.f); }

// LDS row strides (h16 elements) — 16B multiples, non-pow2.
#define S40  40
#define S56  56
#define S72  72
#define S104 104
#define SO2  136

// packed-weight element offsets in d_ws (h16 elements)
enum {
  OFF_WZ1  = 0,      // [32][5][32]
  OFF_WOUT = 5120,   // [32][5][32]
  OFF_WTE1 = 10240,  // [32][5][32]
  OFF_WCM1 = 15360,  // [32][5][64]
  OFF_WTE0 = 25600,  // [48][5][64]
  OFF_WCM0 = 40960,  // [48][5][96]
  OFF_WM0  = 64000,  // [16][32]  q=koff*4+c (q<20)
  OFF_WM20 = 64512,  // [16][32]
  OFF_WM1  = 65024,  // [32][64]  q=koff*8+c (q<40)
  OFF_WM21 = 67072,  // [32][64]
  OFF_WP   = 69120,  // [48][512] rows jj*5+k (<35)
  PACKED_TOTAL = 93696
};

// ---------------- weight packing ----------------
__global__ void pack_weights(const float* wz1, const float* wout, const float* wte1,
    const float* wcm1, const float* wte0, const float* wcm0,
    const float* wm0, const float* wm20, const float* wm1, const float* wm21,
    const float* wproj, h16* wp)
{
  const int t = threadIdx.x;
  auto packBig = [&](const float* src, int O, int C, h16* dst, int Opad, int Cpad){
    const int n = Opad*5*Cpad;
    for (int i = t; i < n; i += blockDim.x){
      int c = i % Cpad; int k = (i / Cpad) % 5; int o = i / (Cpad*5);
      float v = (o < O && c < C) ? src[(o*C + c)*5 + k] : 0.f;
      dst[i] = (h16)v;
    }
  };
  switch (blockIdx.x){
    case 0: packBig(wz1, 24, 32, wp+OFF_WZ1, 32, 32); break;
    case 1: packBig(wout, 24, 24, wp+OFF_WOUT, 32, 32); break;
    case 2: packBig(wte1, 24, 32, wp+OFF_WTE1, 32, 32); break;
    case 3: packBig(wcm1, 24, 48, wp+OFF_WCM1, 32, 64); break;
    case 4: packBig(wte0, 48, 64, wp+OFF_WTE0, 48, 64); break;
    case 5: packBig(wcm0, 48, 96, wp+OFF_WCM0, 48, 96); break;
    case 6: {
      for (int i = t; i < 512; i += blockDim.x){
        int q = i & 31, o = i >> 5; float v = 0.f;
        if (o < 8 && q < 20){ int k = q >> 2, c = q & 3; v = wm0[(o*4 + c)*5 + k]; }
        wp[OFF_WM0 + i] = (h16)v;
      }
      for (int i = t; i < 512; i += blockDim.x){
        int q = i & 31, o = i >> 5; float v = 0.f;
        if (o < 8 && q < 20){ int k = q >> 2, c = q & 3; v = wm20[(o*4 + c)*5 + k]; }
        wp[OFF_WM20 + i] = (h16)v;
      }
    } break;
    case 7: {
      for (int i = t; i < 2048; i += blockDim.x){
        int q = i & 63, o = i >> 6; float v = 0.f;
        if (o < 24 && q < 40){ int k = q >> 3, c = q & 7; v = wm1[(o*8 + c)*5 + k]; }
        wp[OFF_WM1 + i] = (h16)v;
      }
      for (int i = t; i < 2048; i += blockDim.x){
        int q = i & 63, o = i >> 6; float v = 0.f;
        if (o < 24 && q < 40){ int k = q >> 3, c = q & 7; v = wm21[(o*8 + c)*5 + k]; }
        wp[OFF_WM21 + i] = (h16)v;
      }
    } break;
    case 8: {
      for (int i = t; i < 48*512; i += blockDim.x){
        int d = i & 511, r = i >> 9; float v = 0.f;
        if (r < 35){ int jj = r / 5, k = r - jj*5; v = wproj[(jj*512 + d)*5 + k]; }
        wp[OFF_WP + i] = (h16)v;
      }
    } break;
  }
}

// ---------------- device helpers ----------------

// Global [C][512] fp32 -> LDS XT[row=d][col=c] h16 (transposed), zero outside d/c range.
__device__ __forceinline__ void loadT(const float* __restrict__ src, int C, int CB16,
    h16* __restrict__ XT, int S, int co, int d0, int wave, int lane)
{
  const int m = lane & 15, q = lane >> 4;
  const int UNITS = CB16*9;
  for (int u = wave; u < UNITS; u += 8){
    const int cb = u / 9, db = u - cb*9;
    const int row = db*16 + m;
    const int dg = d0 - 8 + row;
    const bool dok = ((unsigned)dg < 512u);
    const int cbase = cb*16 + q*4;
    h16x4 pk;
    #pragma unroll
    for (int i = 0; i < 4; ++i){
      const int c = cbase + i;
      float v = (dok && c < C) ? src[c*512 + dg] : 0.f;
      pk[i] = (h16)v;
    }
    *(h16x4*)(XT + row*S + co + cbase) = pk;
  }
}

__device__ __forceinline__ void zeroCols(h16* XT, int S, int c0, int nc, int tid){
  for (int i = tid; i < 144*nc; i += 512){
    const int r = i / nc, c = i - r*nc;
    XT[r*S + c0 + c] = (h16)0.f;
  }
}

// Conv-GEMM over a 144-row XT tile. CB = K-blocks of 32. EPI 0: s = prev + acc (no elu).
// EPI 1: elu(acc). Stores ZERO for rows whose global d is outside [0,512).
template<int CB, int EPI>
__device__ __forceinline__ void convGemm(const h16* __restrict__ XT, int S,
    const h16* __restrict__ Wp, h16* __restrict__ XTo, int So, int co,
    int OT, int Oreal, int d0, int wave, int lane)
{
  const int m = lane & 15, kg = lane >> 4;
  const int Cpad = CB*32;
  const int NT = OT*9;
  h16x8 B[5][CB];
  int otPrev = -1;
  for (int tix = wave; tix < NT; tix += 8){
    const int ot = tix / 9, rt = tix - ot*9;
    if (ot != otPrev){
      otPrev = ot;
      const int o = ot*16 + m;
      const h16* wb = Wp + o*5*Cpad + kg*8;
      #pragma unroll
      for (int k = 0; k < 5; ++k)
        #pragma unroll
        for (int cb = 0; cb < CB; ++cb)
          B[k][cb] = *(const h16x8*)(wb + k*Cpad + cb*32);
    }
    f32x4 acc = {0.f,0.f,0.f,0.f};
    const int rbase = rt*16 + m - 2;
    #pragma unroll
    for (int k = 0; k < 5; ++k){
      const int r = clampi(rbase + k, 0, 143);
      const h16* ap = XT + r*S + kg*8;
      #pragma unroll
      for (int cb = 0; cb < CB; ++cb)
        acc = MFMA16(*(const h16x8*)(ap + cb*32), B[k][cb], acc);
    }
    const int o = ot*16 + m;
    if (o < Oreal){
      #pragma unroll
      for (int r4 = 0; r4 < 4; ++r4){
        const int row = rt*16 + kg*4 + r4;
        const bool dz = ((unsigned)(d0 - 8 + row) < 512u);   // zero-pad semantics
        float v = acc[r4];
        h16* p = XTo + row*So + co + o;
        if (EPI == 0) *p = dz ? (h16)((float)(*p) + v) : (h16)0.f;
        else          *p = dz ? (h16)eluf(v)           : (h16)0.f;
      }
    }
  }
}

// chunk-merge step=4 -> out1 cols 8j..8j+8
__device__ __forceinline__ void chunk4(const h16* __restrict__ out0, const h16* __restrict__ lt1,
    const h16* __restrict__ wA, const h16* __restrict__ wB, h16* __restrict__ out1,
    int d0, int wave, int lane)
{
  const int m = lane & 15, kg = lane >> 4;
  const h16x8 bA = *(const h16x8*)(wA + m*32 + kg*8);
  const h16x8 bB = *(const h16x8*)(wB + m*32 + kg*8);
  for (int tix = wave; tix < 54; tix += 8){
    const int j = tix / 9, rt = tix - j*9;
    const int rb = rt*16 + m;
    const int r0 = clampi(rb + 2*kg - 2, 0, 143);
    const int r1 = clampi(rb + 2*kg - 1, 0, 143);
    h16x4 lo = *(const h16x4*)(out0 + r0*S40 + 4*j);
    h16x4 hi = *(const h16x4*)(out0 + r1*S40 + 4*j);
    h16x8 a = __builtin_shufflevector(lo, hi, 0,1,2,3,4,5,6,7);
    f32x4 accA = {0.f,0.f,0.f,0.f};
    accA = MFMA16(a, bA, accA);
    lo = *(const h16x4*)(lt1 + r0*S40 + 4*j);
    hi = *(const h16x4*)(lt1 + r1*S40 + 4*j);
    a = __builtin_shufflevector(lo, hi, 0,1,2,3,4,5,6,7);
    f32x4 accB = {0.f,0.f,0.f,0.f};
    accB = MFMA16(a, bB, accB);
    if (m < 8){
      #pragma unroll
      for (int r4 = 0; r4 < 4; ++r4){
        const int row = rt*16 + kg*4 + r4;
        const bool dz = ((unsigned)(d0 - 8 + row) < 512u);
        out1[row*S56 + 8*j + m] = dz ? (h16)(eluf(accA[r4]) + eluf(accB[r4])) : (h16)0.f;
      }
    }
  }
}

// chunk-merge step=8 -> OUT2T[p_local][dloc] (rows 24..31 get exact zeros via zero-B)
__device__ __forceinline__ void chunk8(const h16* __restrict__ out1, const h16* __restrict__ lt0,
    const h16* __restrict__ wA, const h16* __restrict__ wB, h16* __restrict__ o2t,
    int j, int wave, int lane)
{
  const int m = lane & 15, kg = lane >> 4;
  for (int tix = wave; tix < 16; tix += 8){
    const int ot = tix >> 3, rt = tix & 7;
    const int o = ot*16 + m;
    const h16x8 bA0 = *(const h16x8*)(wA + o*64 + kg*8);
    const h16x8 bA1 = *(const h16x8*)(wA + o*64 + 32 + kg*8);
    const h16x8 bB0 = *(const h16x8*)(wB + o*64 + kg*8);
    const h16x8 bB1 = *(const h16x8*)(wB + o*64 + 32 + kg*8);
    const int rb = rt*16 + m + 8;
    const int rA0 = rb + kg - 2;
    const int rA1 = clampi(rb + kg + 2, 0, 143);
    h16x8 a0 = *(const h16x8*)(out1 + rA0*S56 + 8*j);
    h16x8 a1 = *(const h16x8*)(out1 + rA1*S56 + 8*j);
    f32x4 accA = {0.f,0.f,0.f,0.f};
    accA = MFMA16(a0, bA0, accA);
    accA = MFMA16(a1, bA1, accA);
    a0 = *(const h16x8*)(lt0 + rA0*S56 + 8*j);
    a1 = *(const h16x8*)(lt0 + rA1*S56 + 8*j);
    f32x4 accB = {0.f,0.f,0.f,0.f};
    accB = MFMA16(a0, bB0, accB);
    accB = MFMA16(a1, bB1, accB);
    h16x4 pk;
    #pragma unroll
    for (int r4 = 0; r4 < 4; ++r4)
      pk[r4] = (h16)(eluf(accA[r4]) + eluf(accB[r4]));
    *(h16x4*)(o2t + o*SO2 + rt*16 + kg*4) = pk;
  }
}

// proj partial: PROJ[jjk][24j + p] += sum_dloc WP[jjk][d0+dloc] * OUT2T[p][dloc]
__device__ __forceinline__ void projAcc(const h16* __restrict__ WPp, const h16* __restrict__ o2t,
    float* __restrict__ PROJ, int j, int d0, int wave, int lane)
{
  const int m = lane & 15, kg = lane >> 4;
  for (int tix = wave; tix < 6; tix += 8){
    const int ct = tix & 1, rt = tix >> 1;
    f32x4 acc = {0.f,0.f,0.f,0.f};
    const h16* ap = WPp + (rt*16 + m)*512 + d0 + kg*8;
    const h16* bp = o2t + (ct*16 + m)*SO2 + kg*8;
    #pragma unroll
    for (int ks = 0; ks < 4; ++ks)
      acc = MFMA16(*(const h16x8*)(ap + ks*32), *(const h16x8*)(bp + ks*32), acc);
    const int pl = ct*16 + m;
    if (pl < 24){
      #pragma unroll
      for (int r4 = 0; r4 < 4; ++r4){
        const int rowm = rt*16 + kg*4 + r4;
        if (rowm < 35) PROJ[rowm*144 + j*24 + pl] += acc[r4];
      }
    }
  }
}

// ---------------- main fused kernel: one workgroup per batch element ----------------
__global__ __launch_bounds__(512, 2) void decoder_fused(
    const float* __restrict__ enc_true, const float* __restrict__ enc_pred,
    const float* __restrict__ lot0, const float* __restrict__ lot1,
    const float* __restrict__ lop0, const float* __restrict__ lop1,
    const h16* __restrict__ wp, const float* __restrict__ w_lin,
    const float* __restrict__ b_lin, float* __restrict__ out)
{
  __shared__ __align__(16) char smem[110144];
  float* PROJ = (float*)smem;                       // [35][144] fp32
  h16* B1 = (h16*)(smem + 20160);                   // s / cc1 / cc0
  h16* B2 = (h16*)(smem + 50112);                   // true/lot1/lot0/lt0
  h16* B3 = (h16*)(smem + 70848);                   // out0 -> OUT2T
  h16* B4 = (h16*)(smem + 82368);                   // lt1 -> proj final
  h16* B5 = (h16*)(smem + 93888);                   // out1

  const int b = blockIdx.x;
  const int tid = threadIdx.x;
  const int wave = tid >> 6, lane = tid & 63;

  const float* p_true = enc_true + (size_t)b*32*512;
  const float* p_pred = enc_pred + (size_t)b*24*512;
  const float* p_lot1 = lot1 + (size_t)b*32*512;
  const float* p_lop1 = lop1 + (size_t)b*24*512;
  const float* p_lot0 = lot0 + (size_t)b*64*512;
  const float* p_lop0 = lop0 + (size_t)b*48*512;

  for (int i = tid; i < 35*144; i += 512) PROJ[i] = 0.f;
  __syncthreads();

  for (int t = 0; t < 4; ++t){
    const int d0 = t*128;

    loadT(p_true, 32, 2, B2, S40, 0, d0, wave, lane);
    loadT(p_pred, 24, 2, B1, S40, 0, d0, wave, lane);
    __syncthreads();

    // S1: et = conv(true); s = pred + et (RMW into B1)
    convGemm<1,0>(B2, S40, wp+OFF_WZ1, B1, S40, 0, 2, 24, d0, wave, lane);
    __syncthreads();

    // S2: out0 = elu(conv(s)) -> B3 ; prefetch lot1 -> B2
    convGemm<1,1>(B1, S40, wp+OFF_WOUT, B3, S40, 0, 2, 24, d0, wave, lane);
    loadT(p_lot1, 32, 2, B2, S40, 0, d0, wave, lane);
    __syncthreads();

    // S3: lt1a -> cc1[,0:24) ; lop1 -> cc1[,24:56) ; zero cc1[,56:64)
    convGemm<1,1>(B2, S40, wp+OFF_WTE1, B1, S72, 0, 2, 24, d0, wave, lane);
    loadT(p_lop1, 24, 2, B1, S72, 24, d0, wave, lane);
    zeroCols(B1, S72, 56, 8, tid);
    __syncthreads();

    // S4: lt1 = elu(conv(cc1)) -> B4 ; prefetch lot0 -> B2
    convGemm<2,1>(B1, S72, wp+OFF_WCM1, B4, S40, 0, 2, 24, d0, wave, lane);
    loadT(p_lot0, 64, 4, B2, S72, 0, d0, wave, lane);
    __syncthreads();

    // S5: out1 = chunk_merge(out0, lt1, step=4) -> B5
    chunk4(B3, B4, wp+OFF_WM0, wp+OFF_WM20, B5, d0, wave, lane);
    __syncthreads();

    // S6: lt0a -> cc0[,0:48) ; lop0 -> cc0[,48:96)
    convGemm<2,1>(B2, S72, wp+OFF_WTE0, B1, S104, 0, 3, 48, d0, wave, lane);
    loadT(p_lop0, 48, 3, B1, S104, 48, d0, wave, lane);
    __syncthreads();

    // S7: lt0 = elu(conv(cc0)) -> B2
    convGemm<3,1>(B1, S104, wp+OFF_WCM0, B2, S56, 0, 3, 48, d0, wave, lane);
    __syncthreads();

    // S8: per chunk: out2 chunk -> OUT2T, fold into PROJ
    for (int j = 0; j < 6; ++j){
      chunk8(B5, B2, wp+OFF_WM1, wp+OFF_WM21, B3, j, wave, lane);
      __syncthreads();
      projAcc(wp+OFF_WP, B3, PROJ, j, d0, wave, lane);
      __syncthreads();
    }
  }

  // Final: circular-combine PROJ -> proj[7][144], then Linear(144,144) + bias.
  float* projF = (float*)B4;
  for (int i = tid; i < 7*144; i += 512){
    const int jj = i / 144, p = i - jj*144;
    float s = 0.f;
    #pragma unroll
    for (int k = 0; k < 5; ++k){
      int pp = p + k - 2; pp = (pp + 144) % 144;
      s += PROJ[(jj*5 + k)*144 + pp];
    }
    projF[i] = s;
  }
  __syncthreads();
  for (int i = tid; i < 1008; i += 512){
    const int o = i / 7, jj = i - o*7;
    float acc = b_lin[o];
    const float* wl = w_lin + o*144;
    const float* pr = (const float*)projF + jj*144;
    for (int p = 0; p < 144; ++p) acc += pr[p] * wl[p];
    out[(size_t)b*1008 + i] = acc;
  }
}

extern "C" void kernel_launch(void* const* d_in, const int* in_sizes, int n_in,
                              void* d_out, int out_size, void* d_ws, size_t ws_size,
                              hipStream_t stream)
{
  if (ws_size < (size_t)PACKED_TOTAL * sizeof(h16)) return;
  h16* wp = (h16*)d_ws;
  pack_weights<<<9, 256, 0, stream>>>(
      (const float*)d_in[6],  // w_conv_z1
      (const float*)d_in[7],  // w_conv_output
      (const float*)d_in[9],  // w_te1
      (const float*)d_in[11], // w_cm1
      (const float*)d_in[8],  // w_te0
      (const float*)d_in[10], // w_cm0
      (const float*)d_in[12], // w_m0
      (const float*)d_in[13], // w_m20
      (const float*)d_in[14], // w_m1
      (const float*)d_in[15], // w_m21
      (const float*)d_in[16], // w_proj
      wp);
  decoder_fused<<<512, 512, 0, stream>>>(
      (const float*)d_in[0], (const float*)d_in[1],
      (const float*)d_in[2], (const float*)d_in[3],
      (const float*)d_in[4], (const float*)d_in[5],
      wp, (const float*)d_in[17], (const float*)d_in[18],
      (float*)d_out);
}

// Round 3
// 734.151 us; speedup vs baseline: 1.1535x; 1.1535x over previous
//
#include <hip/hip_runtime.h>
#include <hip/hip_bf16.h>

// Decoder_12249246728712 — fused fp16-MFMA, TD=64 / 2 workgroups per CU.
//  * Conv stages as GEMMs OUT[d][o] = sum_{k,c} XT[d+k-2][c] * W[o][c][k];
//    XT transposed in LDS, non-pow2 16B-aligned strides.
//  * d-tile = 64 (+8 halo each side -> 80 rows): LDS 79,296 B -> 2 WG/CU
//    (16 waves/CU) to fix the r2 latency-bound profile (occ 24%, all pipes idle).
//  * OUT2T double-buffered: 1 barrier per S8 chunk instead of 2.
//  * Zero-pad semantics at every stage store (global d outside [0,512) -> 0).

typedef _Float16 h16;
typedef _Float16 h16x8 __attribute__((ext_vector_type(8)));
typedef _Float16 h16x4 __attribute__((ext_vector_type(4)));
typedef float    f32x4 __attribute__((ext_vector_type(4)));

#define MFMA16(a,b,c) __builtin_amdgcn_mfma_f32_16x16x32_f16((a),(b),(c),0,0,0)

__device__ __forceinline__ int clampi(int x, int lo, int hi){ return x < lo ? lo : (x > hi ? hi : x); }
__device__ __forceinline__ float eluf(float v){ return v > 0.f ? v : (__expf(v) - 1.f); }

// LDS row strides (h16 elements) — 16B multiples, non-pow2.
#define S40  40
#define S56  56
#define S72  72
#define S104 104
#define SO2  72     // OUT2T [32][64 used]

#define ROWS 80     // 8-row halo + 64 + 8-row halo
#define RT5  5      // row-tiles of 16

// packed-weight element offsets in d_ws (h16 elements)
enum {
  OFF_WZ1  = 0,      // [32][5][32]
  OFF_WOUT = 5120,   // [32][5][32]
  OFF_WTE1 = 10240,  // [32][5][32]
  OFF_WCM1 = 15360,  // [32][5][64]
  OFF_WTE0 = 25600,  // [48][5][64]
  OFF_WCM0 = 40960,  // [48][5][96]
  OFF_WM0  = 64000,  // [16][32]  q=koff*4+c (q<20)
  OFF_WM20 = 64512,  // [16][32]
  OFF_WM1  = 65024,  // [32][64]  q=koff*8+c (q<40)
  OFF_WM21 = 67072,  // [32][64]
  OFF_WP   = 69120,  // [48][512] rows jj*5+k (<35)
  PACKED_TOTAL = 93696
};

// ---------------- weight packing ----------------
__global__ void pack_weights(const float* wz1, const float* wout, const float* wte1,
    const float* wcm1, const float* wte0, const float* wcm0,
    const float* wm0, const float* wm20, const float* wm1, const float* wm21,
    const float* wproj, h16* wp)
{
  const int t = threadIdx.x;
  auto packBig = [&](const float* src, int O, int C, h16* dst, int Opad, int Cpad){
    const int n = Opad*5*Cpad;
    for (int i = t; i < n; i += blockDim.x){
      int c = i % Cpad; int k = (i / Cpad) % 5; int o = i / (Cpad*5);
      float v = (o < O && c < C) ? src[(o*C + c)*5 + k] : 0.f;
      dst[i] = (h16)v;
    }
  };
  switch (blockIdx.x){
    case 0: packBig(wz1, 24, 32, wp+OFF_WZ1, 32, 32); break;
    case 1: packBig(wout, 24, 24, wp+OFF_WOUT, 32, 32); break;
    case 2: packBig(wte1, 24, 32, wp+OFF_WTE1, 32, 32); break;
    case 3: packBig(wcm1, 24, 48, wp+OFF_WCM1, 32, 64); break;
    case 4: packBig(wte0, 48, 64, wp+OFF_WTE0, 48, 64); break;
    case 5: packBig(wcm0, 48, 96, wp+OFF_WCM0, 48, 96); break;
    case 6: {
      for (int i = t; i < 512; i += blockDim.x){
        int q = i & 31, o = i >> 5; float v = 0.f;
        if (o < 8 && q < 20){ int k = q >> 2, c = q & 3; v = wm0[(o*4 + c)*5 + k]; }
        wp[OFF_WM0 + i] = (h16)v;
      }
      for (int i = t; i < 512; i += blockDim.x){
        int q = i & 31, o = i >> 5; float v = 0.f;
        if (o < 8 && q < 20){ int k = q >> 2, c = q & 3; v = wm20[(o*4 + c)*5 + k]; }
        wp[OFF_WM20 + i] = (h16)v;
      }
    } break;
    case 7: {
      for (int i = t; i < 2048; i += blockDim.x){
        int q = i & 63, o = i >> 6; float v = 0.f;
        if (o < 24 && q < 40){ int k = q >> 3, c = q & 7; v = wm1[(o*8 + c)*5 + k]; }
        wp[OFF_WM1 + i] = (h16)v;
      }
      for (int i = t; i < 2048; i += blockDim.x){
        int q = i & 63, o = i >> 6; float v = 0.f;
        if (o < 24 && q < 40){ int k = q >> 3, c = q & 7; v = wm21[(o*8 + c)*5 + k]; }
        wp[OFF_WM21 + i] = (h16)v;
      }
    } break;
    case 8: {
      for (int i = t; i < 48*512; i += blockDim.x){
        int d = i & 511, r = i >> 9; float v = 0.f;
        if (r < 35){ int jj = r / 5, k = r - jj*5; v = wproj[(jj*512 + d)*5 + k]; }
        wp[OFF_WP + i] = (h16)v;
      }
    } break;
  }
}

// ---------------- device helpers ----------------

// Global [C][512] fp32 -> LDS XT[row=d][col=c] h16 (transposed), zero outside range.
__device__ __forceinline__ void loadT(const float* __restrict__ src, int C, int CB16,
    h16* __restrict__ XT, int S, int co, int d0, int wave, int lane)
{
  const int m = lane & 15, q = lane >> 4;
  const int UNITS = CB16*RT5;
  for (int u = wave; u < UNITS; u += 8){
    const int cb = u / RT5, db = u - cb*RT5;
    const int row = db*16 + m;
    const int dg = d0 - 8 + row;
    const bool dok = ((unsigned)dg < 512u);
    const int cbase = cb*16 + q*4;
    h16x4 pk;
    #pragma unroll
    for (int i = 0; i < 4; ++i){
      const int c = cbase + i;
      float v = (dok && c < C) ? src[c*512 + dg] : 0.f;
      pk[i] = (h16)v;
    }
    *(h16x4*)(XT + row*S + co + cbase) = pk;
  }
}

__device__ __forceinline__ void zeroCols(h16* XT, int S, int c0, int nc, int tid){
  for (int i = tid; i < ROWS*nc; i += 512){
    const int r = i / nc, c = i - r*nc;
    XT[r*S + c0 + c] = (h16)0.f;
  }
}

// Conv-GEMM over an 80-row XT tile. CB = K-blocks of 32. EPI 0: s = prev + acc.
// EPI 1: elu(acc). Stores ZERO for rows whose global d is outside [0,512).
template<int CB, int EPI>
__device__ __forceinline__ void convGemm(const h16* __restrict__ XT, int S,
    const h16* __restrict__ Wp, h16* __restrict__ XTo, int So, int co,
    int OT, int Oreal, int d0, int wave, int lane)
{
  const int m = lane & 15, kg = lane >> 4;
  const int Cpad = CB*32;
  const int NT = OT*RT5;
  h16x8 B[5][CB];
  int otPrev = -1;
  for (int tix = wave; tix < NT; tix += 8){
    const int ot = tix / RT5, rt = tix - ot*RT5;
    if (ot != otPrev){
      otPrev = ot;
      const int o = ot*16 + m;
      const h16* wb = Wp + o*5*Cpad + kg*8;
      #pragma unroll
      for (int k = 0; k < 5; ++k)
        #pragma unroll
        for (int cb = 0; cb < CB; ++cb)
          B[k][cb] = *(const h16x8*)(wb + k*Cpad + cb*32);
    }
    f32x4 acc = {0.f,0.f,0.f,0.f};
    const int rbase = rt*16 + m - 2;
    #pragma unroll
    for (int k = 0; k < 5; ++k){
      const int r = clampi(rbase + k, 0, ROWS-1);
      const h16* ap = XT + r*S + kg*8;
      #pragma unroll
      for (int cb = 0; cb < CB; ++cb)
        acc = MFMA16(*(const h16x8*)(ap + cb*32), B[k][cb], acc);
    }
    const int o = ot*16 + m;
    if (o < Oreal){
      #pragma unroll
      for (int r4 = 0; r4 < 4; ++r4){
        const int row = rt*16 + kg*4 + r4;
        const bool dz = ((unsigned)(d0 - 8 + row) < 512u);   // zero-pad semantics
        float v = acc[r4];
        h16* p = XTo + row*So + co + o;
        if (EPI == 0) *p = dz ? (h16)((float)(*p) + v) : (h16)0.f;
        else          *p = dz ? (h16)eluf(v)           : (h16)0.f;
      }
    }
  }
}

// chunk-merge step=4 -> out1 cols 8j..8j+8
__device__ __forceinline__ void chunk4(const h16* __restrict__ out0, const h16* __restrict__ lt1,
    const h16* __restrict__ wA, const h16* __restrict__ wB, h16* __restrict__ out1,
    int d0, int wave, int lane)
{
  const int m = lane & 15, kg = lane >> 4;
  const h16x8 bA = *(const h16x8*)(wA + m*32 + kg*8);
  const h16x8 bB = *(const h16x8*)(wB + m*32 + kg*8);
  for (int tix = wave; tix < 6*RT5; tix += 8){
    const int j = tix / RT5, rt = tix - j*RT5;
    const int rb = rt*16 + m;
    const int r0 = clampi(rb + 2*kg - 2, 0, ROWS-1);
    const int r1 = clampi(rb + 2*kg - 1, 0, ROWS-1);
    h16x4 lo = *(const h16x4*)(out0 + r0*S40 + 4*j);
    h16x4 hi = *(const h16x4*)(out0 + r1*S40 + 4*j);
    h16x8 a = __builtin_shufflevector(lo, hi, 0,1,2,3,4,5,6,7);
    f32x4 accA = {0.f,0.f,0.f,0.f};
    accA = MFMA16(a, bA, accA);
    lo = *(const h16x4*)(lt1 + r0*S40 + 4*j);
    hi = *(const h16x4*)(lt1 + r1*S40 + 4*j);
    a = __builtin_shufflevector(lo, hi, 0,1,2,3,4,5,6,7);
    f32x4 accB = {0.f,0.f,0.f,0.f};
    accB = MFMA16(a, bB, accB);
    if (m < 8){
      #pragma unroll
      for (int r4 = 0; r4 < 4; ++r4){
        const int row = rt*16 + kg*4 + r4;
        const bool dz = ((unsigned)(d0 - 8 + row) < 512u);
        out1[row*S56 + 8*j + m] = dz ? (h16)(eluf(accA[r4]) + eluf(accB[r4])) : (h16)0.f;
      }
    }
  }
}

// chunk-merge step=8 -> OUT2T[p_local][dloc] (rows 24..31 exact zeros via zero-B)
__device__ __forceinline__ void chunk8(const h16* __restrict__ out1, const h16* __restrict__ lt0,
    const h16* __restrict__ wA, const h16* __restrict__ wB, h16* __restrict__ o2t,
    int j, int wave, int lane)
{
  const int m = lane & 15, kg = lane >> 4;
  for (int tix = wave; tix < 8; tix += 8){
    const int ot = tix >> 2, rt = tix & 3;
    const int o = ot*16 + m;
    const h16x8 bA0 = *(const h16x8*)(wA + o*64 + kg*8);
    const h16x8 bA1 = *(const h16x8*)(wA + o*64 + 32 + kg*8);
    const h16x8 bB0 = *(const h16x8*)(wB + o*64 + kg*8);
    const h16x8 bB1 = *(const h16x8*)(wB + o*64 + 32 + kg*8);
    const int rb = rt*16 + m + 8;                  // dloc row
    const int rA0 = rb + kg - 2;
    const int rA1 = clampi(rb + kg + 2, 0, ROWS-1);
    h16x8 a0 = *(const h16x8*)(out1 + rA0*S56 + 8*j);
    h16x8 a1 = *(const h16x8*)(out1 + rA1*S56 + 8*j);
    f32x4 accA = {0.f,0.f,0.f,0.f};
    accA = MFMA16(a0, bA0, accA);
    accA = MFMA16(a1, bA1, accA);
    a0 = *(const h16x8*)(lt0 + rA0*S56 + 8*j);
    a1 = *(const h16x8*)(lt0 + rA1*S56 + 8*j);
    f32x4 accB = {0.f,0.f,0.f,0.f};
    accB = MFMA16(a0, bB0, accB);
    accB = MFMA16(a1, bB1, accB);
    h16x4 pk;
    #pragma unroll
    for (int r4 = 0; r4 < 4; ++r4)
      pk[r4] = (h16)(eluf(accA[r4]) + eluf(accB[r4]));
    *(h16x4*)(o2t + o*SO2 + rt*16 + kg*4) = pk;
  }
}

// proj partial: PROJ[jjk][24j + p] += sum_dloc WP[jjk][d0+dloc] * OUT2T[p][dloc]
__device__ __forceinline__ void projAcc(const h16* __restrict__ WPp, const h16* __restrict__ o2t,
    float* __restrict__ PROJ, int j, int d0, int wave, int lane)
{
  const int m = lane & 15, kg = lane >> 4;
  for (int tix = wave; tix < 6; tix += 8){
    const int ct = tix & 1, rt = tix >> 1;
    f32x4 acc = {0.f,0.f,0.f,0.f};
    const h16* ap = WPp + (rt*16 + m)*512 + d0 + kg*8;
    const h16* bp = o2t + (ct*16 + m)*SO2 + kg*8;
    #pragma unroll
    for (int ks = 0; ks < 2; ++ks)
      acc = MFMA16(*(const h16x8*)(ap + ks*32), *(const h16x8*)(bp + ks*32), acc);
    const int pl = ct*16 + m;
    if (pl < 24){
      #pragma unroll
      for (int r4 = 0; r4 < 4; ++r4){
        const int rowm = rt*16 + kg*4 + r4;
        if (rowm < 35) PROJ[rowm*144 + j*24 + pl] += acc[r4];
      }
    }
  }
}

// ---------------- main fused kernel: one workgroup per batch element ----------------
__global__ __launch_bounds__(512, 4) void decoder_fused(
    const float* __restrict__ enc_true, const float* __restrict__ enc_pred,
    const float* __restrict__ lot0, const float* __restrict__ lot1,
    const float* __restrict__ lop0, const float* __restrict__ lop1,
    const h16* __restrict__ wp, const float* __restrict__ w_lin,
    const float* __restrict__ b_lin, float* __restrict__ out)
{
  // LDS arena: 79,296 B -> 2 WGs/CU (158,592 <= 163,840).
  __shared__ __align__(16) char smem[79296];
  float* PROJ = (float*)smem;                       // [35][144] fp32   20160 B
  h16* B1 = (h16*)(smem + 20160);                   // s / cc1 / cc0    16640 B (80xS104)
  h16* B2 = (h16*)(smem + 36800);                   // true/lot/lt0     11520 B (80xS72)
  h16* B3 = (h16*)(smem + 48320);                   // out0              6400 B (80xS40)
  h16* B4 = (h16*)(smem + 54720);                   // lt1 / projF       6400 B (80xS40)
  h16* B5 = (h16*)(smem + 61120);                   // out1              8960 B (80xS56)
  h16* O2a = (h16*)(smem + 70080);                  // OUT2T buf 0       4608 B (32xSO2)
  h16* O2b = (h16*)(smem + 74688);                  // OUT2T buf 1       4608 B

  const int b = blockIdx.x;
  const int tid = threadIdx.x;
  const int wave = tid >> 6, lane = tid & 63;

  const float* p_true = enc_true + (size_t)b*32*512;
  const float* p_pred = enc_pred + (size_t)b*24*512;
  const float* p_lot1 = lot1 + (size_t)b*32*512;
  const float* p_lop1 = lop1 + (size_t)b*24*512;
  const float* p_lot0 = lot0 + (size_t)b*64*512;
  const float* p_lop0 = lop0 + (size_t)b*48*512;

  for (int i = tid; i < 35*144; i += 512) PROJ[i] = 0.f;
  __syncthreads();

  for (int t = 0; t < 8; ++t){
    const int d0 = t*64;

    loadT(p_true, 32, 2, B2, S40, 0, d0, wave, lane);
    loadT(p_pred, 24, 2, B1, S40, 0, d0, wave, lane);
    __syncthreads();

    // S1: et = conv(true); s = pred + et (RMW into B1)
    convGemm<1,0>(B2, S40, wp+OFF_WZ1, B1, S40, 0, 2, 24, d0, wave, lane);
    __syncthreads();

    // S2: out0 = elu(conv(s)) -> B3 ; prefetch lot1 -> B2
    convGemm<1,1>(B1, S40, wp+OFF_WOUT, B3, S40, 0, 2, 24, d0, wave, lane);
    loadT(p_lot1, 32, 2, B2, S40, 0, d0, wave, lane);
    __syncthreads();

    // S3: lt1a -> cc1[,0:24) ; lop1 -> cc1[,24:48) ; zero [48:64)
    convGemm<1,1>(B2, S40, wp+OFF_WTE1, B1, S72, 0, 2, 24, d0, wave, lane);
    loadT(p_lop1, 24, 2, B1, S72, 24, d0, wave, lane);
    zeroCols(B1, S72, 56, 8, tid);
    __syncthreads();

    // S4: lt1 = elu(conv(cc1)) -> B4 ; prefetch lot0 -> B2
    convGemm<2,1>(B1, S72, wp+OFF_WCM1, B4, S40, 0, 2, 24, d0, wave, lane);
    loadT(p_lot0, 64, 4, B2, S72, 0, d0, wave, lane);
    __syncthreads();

    // S5: out1 = chunk_merge(out0, lt1, step=4) -> B5
    chunk4(B3, B4, wp+OFF_WM0, wp+OFF_WM20, B5, d0, wave, lane);
    __syncthreads();

    // S6: lt0a -> cc0[,0:48) ; lop0 -> cc0[,48:96)
    convGemm<2,1>(B2, S72, wp+OFF_WTE0, B1, S104, 0, 3, 48, d0, wave, lane);
    loadT(p_lop0, 48, 3, B1, S104, 48, d0, wave, lane);
    __syncthreads();

    // S7: lt0 = elu(conv(cc0)) -> B2
    convGemm<3,1>(B1, S104, wp+OFF_WCM0, B2, S56, 0, 3, 48, d0, wave, lane);
    __syncthreads();

    // S8: per chunk j: out2 chunk -> OUT2T[j&1], fold into PROJ.
    // Double-buffered OUT2T: single barrier per j. projAcc(j) runs concurrently
    // with other waves' chunk8(j+1) (different buffer) — safe.
    for (int j = 0; j < 6; ++j){
      h16* o2 = (j & 1) ? O2b : O2a;
      chunk8(B5, B2, wp+OFF_WM1, wp+OFF_WM21, o2, j, wave, lane);
      __syncthreads();
      projAcc(wp+OFF_WP, o2, PROJ, j, d0, wave, lane);
    }
    // next-t loadT targets (B1,B2) are not touched by projAcc; chunk8(5) readers
    // of B2/B5 all passed the j=5 barrier, so no extra barrier needed here.
  }
  __syncthreads();   // PROJ complete across all waves

  // Final: circular-combine PROJ -> proj[7][144], then Linear(144,144) + bias.
  float* projF = (float*)B4;
  for (int i = tid; i < 7*144; i += 512){
    const int jj = i / 144, p = i - jj*144;
    float s = 0.f;
    #pragma unroll
    for (int k = 0; k < 5; ++k){
      int pp = p + k - 2; pp = (pp + 144) % 144;
      s += PROJ[(jj*5 + k)*144 + pp];
    }
    projF[i] = s;
  }
  __syncthreads();
  for (int i = tid; i < 1008; i += 512){
    const int o = i / 7, jj = i - o*7;
    float acc = b_lin[o];
    const float* wl = w_lin + o*144;
    const float* pr = (const float*)projF + jj*144;
    for (int p = 0; p < 144; ++p) acc += pr[p] * wl[p];
    out[(size_t)b*1008 + i] = acc;
  }
}

extern "C" void kernel_launch(void* const* d_in, const int* in_sizes, int n_in,
                              void* d_out, int out_size, void* d_ws, size_t ws_size,
                              hipStream_t stream)
{
  if (ws_size < (size_t)PACKED_TOTAL * sizeof(h16)) return;
  h16* wp = (h16*)d_ws;
  pack_weights<<<9, 256, 0, stream>>>(
      (const float*)d_in[6],  // w_conv_z1
      (const float*)d_in[7],  // w_conv_output
      (const float*)d_in[9],  // w_te1
      (const float*)d_in[11], // w_cm1
      (const float*)d_in[8],  // w_te0
      (const float*)d_in[10], // w_cm0
      (const float*)d_in[12], // w_m0
      (const float*)d_in[13], // w_m20
      (const float*)d_in[14], // w_m1
      (const float*)d_in[15], // w_m21
      (const float*)d_in[16], // w_proj
      wp);
  decoder_fused<<<512, 512, 0, stream>>>(
      (const float*)d_in[0], (const float*)d_in[1],
      (const float*)d_in[2], (const float*)d_in[3],
      (const float*)d_in[4], (const float*)d_in[5],
      wp, (const float*)d_in[17], (const float*)d_in[18],
      (float*)d_out);
}